// Round 18
// baseline (103.873 us; speedup 1.0000x reference)
//
#include <hip/hip_runtime.h>

// Problem constants
constexpr int NB   = 4;     // batch
constexpr int SEQ  = 2048;  // Q == K
constexpr int CDIM = 128;   // input channels
constexpr int NH   = 8;     // heads
constexpr int HD   = 16;    // head dim

typedef _Float16 h_t;
typedef __attribute__((ext_vector_type(4))) _Float16 h4;
typedef __attribute__((ext_vector_type(8))) _Float16 h8;
typedef __attribute__((ext_vector_type(2))) __fp16   fp2;   // cvt_pkrtz result type
typedef __attribute__((ext_vector_type(4))) float    f4;

// exp(s - 8) == 2^(s*log2e - 8*log2e); log2e folded into W_q at projection
// time, so attn computes 2^(S + BIAS) with one native v_exp_f32 per score.
// Fixed shift => softmax partials are LINEAR: kv-quarter partials add exactly.
constexpr float LOG2E = 1.44269504f;
constexpr float BIAS  = -8.0f * LOG2E;   // -11.5415603

// ---------------------------------------------------------------------------
// Kernel 1: QKV projection as f16 MFMA GEMM — identical to r15-r17 (coalesced
// h4 stores; q/k operand-swapped, v in vF fragment-stream order).
// ---------------------------------------------------------------------------
__global__ __launch_bounds__(256)
void proj(const float* __restrict__ qx, const float* __restrict__ kvx,
          const float* __restrict__ wq, const float* __restrict__ wk,
          const float* __restrict__ wv,
          h_t* __restrict__ qh, h_t* __restrict__ kh, h_t* __restrict__ vF)
{
    const int mat = blockIdx.y;                 // 0=q, 1=k, 2=v
    const int mb  = blockIdx.x * 64;            // row-tile base (8192 rows)
    const int wv_ = threadIdx.x >> 6;           // wave 0..3
    const int ln  = threadIdx.x & 63;
    const int r   = ln & 15, kg = ln >> 4;
    const int stile = mb + wv_ * 16;            // 16-row subtile base
    const int srow  = stile + r;                // X-fragment seq row

    const float* x = (mat == 0) ? qx : kvx;
    const float* w = (mat == 0) ? wq : (mat == 1) ? wk : wv;
    h_t*         o = (mat == 0) ? qh : (mat == 1) ? kh : vF;
    const float ws_ = (mat == 0) ? 0.25f * LOG2E : 1.0f;  // fold scale into W_q

    // X fragments (shared across nt): 16-dim on r (seqrow), k = kg*8+i
    h8 xf[4];
    #pragma unroll
    for (int kc = 0; kc < 4; ++kc) {
        const float* xp = x + (size_t)srow * CDIM + kc * 32 + kg * 8;
        f4 x0 = *(const f4*)xp;
        f4 x1 = *(const f4*)(xp + 4);
        h8 tf;
        #pragma unroll
        for (int i = 0; i < 4; ++i) { tf[i] = (h_t)x0[i]; tf[4 + i] = (h_t)x1[i]; }
        xf[kc] = tf;
    }

    const int b_ = srow >> 11;                  // batch (constant within subtile)
    const int s  = srow & (SEQ - 1);

    #pragma unroll
    for (int nt = 0; nt < 8; ++nt) {            // head = nt (16 out-features)
        f4 acc = {0.f, 0.f, 0.f, 0.f};
        #pragma unroll
        for (int kc = 0; kc < 4; ++kc) {
            const float* wp = w + (size_t)(nt * 16 + r) * CDIM + kc * 32 + kg * 8;
            f4 w0 = *(const f4*)wp;
            f4 w1 = *(const f4*)(wp + 4);
            h8 wf;
            #pragma unroll
            for (int i = 0; i < 4; ++i) {
                wf[i]     = (h_t)(w0[i] * ws_);
                wf[4 + i] = (h_t)(w1[i] * ws_);
            }
            acc = (mat == 2)
                ? __builtin_amdgcn_mfma_f32_16x16x32_f16(xf[kc], wf, acc, 0, 0, 0)
                : __builtin_amdgcn_mfma_f32_16x16x32_f16(wf, xf[kc], acc, 0, 0, 0);
        }
        h4 pk;
        #pragma unroll
        for (int i = 0; i < 4; ++i) pk[i] = (h_t)acc[i];

        if (mat == 2) {
            const int bv = stile >> 11, sv = stile & (SEQ - 1);
            *(h4*)(o + (((size_t)bv * NH + nt) * 128 + (sv >> 4)) * 256 + r * 16 + 4 * kg) = pk;
        } else {
            *(h4*)(o + (((size_t)b_ * NH + nt) * SEQ + s) * HD + 4 * kg) = pk;
        }
    }
}

// ---------------------------------------------------------------------------
// one 16-kv chunk against 4 resident Q-fragments (1024 scores / call)
// ---------------------------------------------------------------------------
__device__ __forceinline__ void chunk4(const h4 kf, const h4 vf,
                                       const h4* qf, const f4& cbias,
                                       const h4& ones, f4* o, f4* ol)
{
    #pragma unroll
    for (int j = 0; j < 4; ++j) {
        f4 s = __builtin_amdgcn_mfma_f32_16x16x16f16(kf, qf[j], cbias, 0, 0, 0);
        const float e0 = __builtin_amdgcn_exp2f(s[0]);
        const float e1 = __builtin_amdgcn_exp2f(s[1]);
        const float e2 = __builtin_amdgcn_exp2f(s[2]);
        const float e3 = __builtin_amdgcn_exp2f(s[3]);
        union { fp2 cc[2]; h4 v; } p;
        p.cc[0] = __builtin_amdgcn_cvt_pkrtz(e0, e1);
        p.cc[1] = __builtin_amdgcn_cvt_pkrtz(e2, e3);
        o[j]  = __builtin_amdgcn_mfma_f32_16x16x16f16(p.v, vf,   o[j],  0, 0, 0);
        ol[j] = __builtin_amdgcn_mfma_f32_16x16x16f16(p.v, ones, ol[j], 0, 0, 0);
    }
}

// ---------------------------------------------------------------------------
// Kernel 2: MFMA flash attention — MAX AMORTIZATION (4 Q-frags/wave).
// r16/r17 proved the limiter is per-score instruction issue; the only
// reducible term left is fixed per-chunk cost (loads, rotates, addressing,
// loop). This round each chunk serves 1024 scores (4 qfrags, 64 q rows/wave)
// — K/V traffic halves again (128 MB). Occupancy spent on ILP
// (__launch_bounds__(512,4), ~80 VGPR): r17 showed 8 waves/SIMD adds nothing.
// Denominator via MFMA-with-ones (lane-local l); kv-quarter split, 4-way
// in-block LDS merge (exact: fixed-shift partials linear), one barrier.
// grid (16 q-tiles of 128, 32 bh), block 512 = 2 q-subs x 4 kv-quarters.
// Tail prefetch overreads <= 1 KB past the quarter — inside the workspace.
// ---------------------------------------------------------------------------
__global__ __launch_bounds__(512, 4)
void attn(const h_t* __restrict__ qh, const h_t* __restrict__ kh,
          const h_t* __restrict__ vF, float* __restrict__ out)
{
    const int bh  = blockIdx.y;                 // b*8 + h
    const int w   = threadIdx.x >> 6;           // wave 0..7
    const int qs  = w & 1;                      // q-subtile (64 rows)
    const int kvq = w >> 1;                     // kv quarter 0..3
    const int ln  = threadIdx.x & 63;
    const int r   = ln & 15, kg = ln >> 4;

    __shared__ float oS[2][3][4][16][17];       // [qsub][kvq-1][qfrag][row][col]
    __shared__ float lS[2][3][4][16];           // [qsub][kvq-1][qfrag][row]

    const size_t hb = (size_t)bh * SEQ * HD;
    const int qb = blockIdx.x * 128 + qs * 64;

    // Q fragments (pre-scaled by log2e/4): B-operand n=q=r, k=d=kg*4+i
    h4 qf[4];
    #pragma unroll
    for (int j = 0; j < 4; ++j)
        qf[j] = *(const h4*)(qh + hb + (size_t)(qb + 16 * j + r) * HD + kg * 4);

    // streaming bases; chunk = 256 halves (512 B/wave); quarter = 32 chunks
    const h_t* kp = kh + hb + kvq * 32 * 256 + r * HD + kg * 4;
    const h_t* vp = vF + hb + kvq * 32 * 256 + r * 16 + kg * 4;

    f4 o[4], ol[4];
    #pragma unroll
    for (int j = 0; j < 4; ++j) {
        o[j]  = (f4){0.f, 0.f, 0.f, 0.f};
        ol[j] = (f4){0.f, 0.f, 0.f, 0.f};
    }
    const f4 cbias = {BIAS, BIAS, BIAS, BIAS};
    const h4 ones  = {(h_t)1.f, (h_t)1.f, (h_t)1.f, (h_t)1.f};

    // 2-deep pipeline prologue
    h4 kfa = *(const h4*)(kp);
    h4 vfa = *(const h4*)(vp);
    h4 kfb = *(const h4*)(kp + 256);
    h4 vfb = *(const h4*)(vp + 256);

    for (int c = 0; c < 32; c += 2) {
        h4 kfn0 = *(const h4*)(kp + (c + 2) * 256);
        h4 vfn0 = *(const h4*)(vp + (c + 2) * 256);
        h4 kfn1 = *(const h4*)(kp + (c + 3) * 256);
        h4 vfn1 = *(const h4*)(vp + (c + 3) * 256);

        chunk4(kfa, vfa, qf, cbias, ones, o, ol);
        chunk4(kfb, vfb, qf, cbias, ones, o, ol);

        kfa = kfn0; vfa = vfn0;
        kfb = kfn1; vfb = vfn1;
    }

    // kv-quarters 1..3 publish partials; quarter 0 merges.
    if (kvq != 0) {
        const int slot = kvq - 1;
        #pragma unroll
        for (int j = 0; j < 4; ++j) {
            #pragma unroll
            for (int reg = 0; reg < 4; ++reg)
                oS[qs][slot][j][4 * kg + reg][r] = o[j][reg];
            if (r == 0) {   // ol replicated over cols; one lane per quad row
                #pragma unroll
                for (int reg = 0; reg < 4; ++reg)
                    lS[qs][slot][j][4 * kg + reg] = ol[j][reg];
            }
        }
    }
    __syncthreads();

    if (kvq == 0) {
        const int b_ = bh >> 3, h = bh & 7;
        #pragma unroll
        for (int j = 0; j < 4; ++j) {
            #pragma unroll
            for (int reg = 0; reg < 4; ++reg) {
                const int row = 4 * kg + reg;
                float O = o[j][reg], L = ol[j][reg];
                #pragma unroll
                for (int sl = 0; sl < 3; ++sl) {
                    O += oS[qs][sl][j][row][r];
                    L += lS[qs][sl][j][row];
                }
                const int q = qb + 16 * j + row;
                out[(((size_t)b_ * SEQ + q) * NH + h) * HD + r] = O / L;
            }
        }
    }
}

// ---------------------------------------------------------------------------
extern "C" void kernel_launch(void* const* d_in, const int* in_sizes, int n_in,
                              void* d_out, int out_size, void* d_ws, size_t ws_size,
                              hipStream_t stream) {
    const float* qx  = (const float*)d_in[0]; // [B,S,C] f32
    const float* kvx = (const float*)d_in[1]; // [B,S,C] f32
    const float* wq  = (const float*)d_in[2]; // [H*D,C] f32
    const float* wk  = (const float*)d_in[3];
    const float* wv  = (const float*)d_in[4];
    float* out = (float*)d_out;               // [B,Q,H,D] f32

    const size_t per = (size_t)NB * NH * SEQ * HD;    // 1,048,576
    // f16 slabs: q | k | vF  (2 MB each)
    h_t* qp = (h_t*)d_ws;
    h_t* kp = qp + per;
    h_t* vp = kp + per;

    proj<<<dim3(128, 3), dim3(256), 0, stream>>>(qx, kvx, wq, wk, wv, qp, kp, vp);
    attn<<<dim3(16, 32), dim3(512), 0, stream>>>(qp, kp, vp, out);
}